// Round 6
// baseline (690.880 us; speedup 1.0000x reference)
//
#include <hip/hip_runtime.h>
#include <hip/hip_bf16.h>

// ---------------------------------------------------------------------------
// LayerNormGRUCell: B=16384, I=H=512
//   G = [x@W_i2h.T | h@W_h2h.T | x@W_hatW.T | h@W_hatU.T]  (16384 x 3072)
//   then per-row: LN segments + gates + tanh + lerp -> h_t (16384 x 512 fp32)
// ws layout (bf16 elements):
//   xb   @ 0         (16384*512)
//   hb   @ 8388608   (16384*512)
//   Wcat @ 16777216  (3072*512)   rows: [W_i2h;W_h2h;W_hatW;W_hatU]
//   Gb   @ 18350080  (16384*3072)
// ---------------------------------------------------------------------------

using f32x4 = __attribute__((ext_vector_type(4))) float;
using s16x8 = __attribute__((ext_vector_type(8))) short;

#define XB_OFF   0ull
#define HB_OFF   8388608ull
#define WB_OFF   16777216ull
#define GB_OFF   18350080ull

// vec4 segment boundaries for the convert kernel
#define CV_X_END   2097152ull
#define CV_H_END   4194304ull
#define CV_W0_END  4325376ull
#define CV_W1_END  4456448ull
#define CV_W2_END  4521984ull
#define CV_W3_END  4587520ull

__device__ __forceinline__ void async_load16(const void* g, void* l) {
  __builtin_amdgcn_global_load_lds(
      (const __attribute__((address_space(1))) unsigned int*)g,
      (__attribute__((address_space(3))) unsigned int*)l, 16, 0, 0);
}

__device__ __forceinline__ float bfraw2f(unsigned short u) {
  union { unsigned int i; float f; } c;
  c.i = ((unsigned int)u) << 16;
  return c.f;
}

// -------------------------- fp32 -> bf16 conversion ------------------------
__global__ __launch_bounds__(256) void convert_kernel(
    const float* __restrict__ x, const float* __restrict__ h,
    const float* __restrict__ w0, const float* __restrict__ w1,
    const float* __restrict__ w2, const float* __restrict__ w3,
    __hip_bfloat16* __restrict__ ws)
{
  const size_t i = (size_t)blockIdx.x * 256 + threadIdx.x;  // vec4 index
  const float* src;
  __hip_bfloat16* dst;
  size_t o;
  if (i < CV_X_END)        { src = x;  dst = ws + XB_OFF;            o = i; }
  else if (i < CV_H_END)   { src = h;  dst = ws + HB_OFF;            o = i - CV_X_END; }
  else if (i < CV_W0_END)  { src = w0; dst = ws + WB_OFF;            o = i - CV_H_END; }
  else if (i < CV_W1_END)  { src = w1; dst = ws + WB_OFF + 524288;   o = i - CV_W0_END; }
  else if (i < CV_W2_END)  { src = w2; dst = ws + WB_OFF + 1048576;  o = i - CV_W1_END; }
  else                     { src = w3; dst = ws + WB_OFF + 1310720;  o = i - CV_W2_END; }
  const float4 v = *(const float4*)(src + 4 * o);
  __hip_bfloat16 t4[4] = {__float2bfloat16(v.x), __float2bfloat16(v.y),
                          __float2bfloat16(v.z), __float2bfloat16(v.w)};
  *(uint2*)(dst + 4 * o) = *(const uint2*)t4;
}

// -------------------------------- GEMM -------------------------------------
// 256x256 tile, BK=32, 8 waves (2Mx4N), 2-slot LDS ring (64 KiB) -> 2 blocks
// co-resident per CU (16 waves): latency hiding via cross-block wave overlap
// (m97/m114 mechanism) instead of deep intra-block pipelining. Stage depth 1:
// slot (t+1)&1 is staged during ktile t; entry wait vmcnt(0) + barrier; the
// drain bubble is covered by the other resident block's waves.
// T1 XCD swizzle, T2 XOR-swizzled LDS, T5 setprio. Full K-loop unroll.
//
// LDS slot layout (per matrix): [256 rows][32 bf16 = 64 B], physical column
// byte cb holds global k-byte (cb ^ swz(row)), swz(row) = ((row>>1)&3)<<4.
// global_load_lds writes linearly; source global address pre-swizzled;
// ds_read applies the same XOR (rule 21).
//
// WAR safety: staging into slot (t+1)&1 issues after the entry barrier of
// ktile t; all reads of that slot's previous contents (ktile t-1) retired
// before that barrier (each wave's lgkmcnt waits precede its barrier).

#define SLOT_BYTES 16384   // 256*32*2
#define LDSB_OFF   32768   // 2 A slots

__device__ __forceinline__ void stage_mat(const char* base, char* slot,
                                          int koff, int wave, int lane) {
#pragma unroll
  for (int i = 0; i < 2; ++i) {
    const int c = wave * 2 + i;                       // 16-row chunk, 1024 B
    const int row = c * 16 + (lane >> 2);
    const int colb = ((lane & 3) * 16) ^ (((lane >> 3) & 3) << 4);  // pre-swz
    async_load16(base + (size_t)row * 1024 + koff + colb,
                 slot + c * 1024 + lane * 16);
  }
}

__global__ __launch_bounds__(512, 4) void gemm_kernel(
    const __hip_bfloat16* __restrict__ xb,
    const __hip_bfloat16* __restrict__ hb,
    const __hip_bfloat16* __restrict__ Wb,
    __hip_bfloat16* __restrict__ G)
{
  // T1: bijective XCD swizzle; nwg=768, 768%8==0, chunk=96 wgs/XCD.
  const int bid = blockIdx.x;
  const int wg  = (bid & 7) * 96 + (bid >> 3);
  const int ntl = wg % 12, mtl = wg / 12;
  const int m0 = mtl * 256, n0 = ntl * 256;
  const int seg = n0 >> 9;  // 512-wide segments: 0,1,4 -> x ; 2,3,5 -> h
  const __hip_bfloat16* A = (seg < 2 || seg == 4) ? xb : hb;

  __shared__ __align__(16) char lds[65536];  // 2-slot ring x (A 16K + B 16K)

  const int tid  = threadIdx.x;
  const int lane = tid & 63;
  const int wave = tid >> 6;
  const int wm = wave >> 2, wn = wave & 3;   // 2 x 4 wave grid, 128x64 each

  const char* Ab = (const char*)A  + (size_t)m0 * 1024;  // row = 512*2 B
  const char* Bb = (const char*)Wb + (size_t)n0 * 1024;

  const int lk = (lane >> 4) * 16;
  const int lr = lane & 15;

  // fragment readers (slot index by ktile t)
  auto rdB = [&](int fn, int t) {
    const int r = wn * 64 + fn * 16 + lr;
    return *(const s16x8*)(lds + LDSB_OFF + (size_t)(t & 1) * SLOT_BYTES +
                           r * 64 + (lk ^ (((r >> 1) & 3) << 4)));
  };
  auto rdA = [&](int fm, int half, int t) {
    const int r = wm * 128 + half * 64 + fm * 16 + lr;
    return *(const s16x8*)(lds + (size_t)(t & 1) * SLOT_BYTES +
                           r * 64 + (lk ^ (((r >> 1) & 3) << 4)));
  };

  f32x4 acc[8][4];
#pragma unroll
  for (int i = 0; i < 8; ++i)
#pragma unroll
    for (int j = 0; j < 4; ++j) acc[i][j] = (f32x4){0.f, 0.f, 0.f, 0.f};

  // prologue: stage slot 0
  stage_mat(Ab, lds, 0, wave, lane);
  stage_mat(Bb, lds + LDSB_OFF, 0, wave, lane);
  asm volatile("s_waitcnt vmcnt(0)" ::: "memory");
  __builtin_amdgcn_s_barrier();

  // K = 512 = 16 ktiles of 32, fully unrolled
#pragma unroll
  for (int t = 0; t < 16; ++t) {
    if (t > 0) {
      asm volatile("s_waitcnt vmcnt(0)" ::: "memory");  // slot t resident
      __builtin_amdgcn_s_barrier();   // all waves done reading slot t-1
    }

    // issue all 12 ds_reads up-front, then stage next slot, then MFMA
    s16x8 b[4], a0[4], a1[4];
#pragma unroll
    for (int fn = 0; fn < 4; ++fn) b[fn] = rdB(fn, t);
#pragma unroll
    for (int fm = 0; fm < 4; ++fm) a0[fm] = rdA(fm, 0, t);
#pragma unroll
    for (int fm = 0; fm < 4; ++fm) a1[fm] = rdA(fm, 1, t);

    if (t < 15) {
      stage_mat(Ab, lds + ((t + 1) & 1) * SLOT_BYTES, (t + 1) * 64, wave, lane);
      stage_mat(Bb, lds + LDSB_OFF + ((t + 1) & 1) * SLOT_BYTES, (t + 1) * 64,
                wave, lane);
    }

    __builtin_amdgcn_s_setprio(1);
#pragma unroll
    for (int fm = 0; fm < 4; ++fm)
#pragma unroll
      for (int fn = 0; fn < 4; ++fn)
        acc[fm][fn] = __builtin_amdgcn_mfma_f32_16x16x32_bf16(
            a0[fm], b[fn], acc[fm][fn], 0, 0, 0);
#pragma unroll
    for (int fm = 0; fm < 4; ++fm)
#pragma unroll
      for (int fn = 0; fn < 4; ++fn)
        acc[4 + fm][fn] = __builtin_amdgcn_mfma_f32_16x16x32_bf16(
            a1[fm], b[fn], acc[4 + fm][fn], 0, 0, 0);
    __builtin_amdgcn_s_setprio(0);
  }

  // epilogue: D lane map (verified): col = lane&15, row = (lane>>4)*4 + reg
  const int mbase = m0 + wm * 128 + ((lane >> 4) << 2);
  const int nbase = n0 + wn * 64 + (lane & 15);
#pragma unroll
  for (int fm = 0; fm < 8; ++fm)
#pragma unroll
    for (int fn = 0; fn < 4; ++fn)
#pragma unroll
      for (int r = 0; r < 4; ++r)
        G[(size_t)(mbase + fm * 16 + r) * 3072 + nbase + fn * 16] =
            __float2bfloat16(acc[fm][fn][r]);
}

// ------------------------------ LN + gates ---------------------------------
__device__ __forceinline__ float4 block_red4(float4 v, float* red, int tid) {
#pragma unroll
  for (int off = 32; off; off >>= 1) {
    v.x += __shfl_down(v.x, off);
    v.y += __shfl_down(v.y, off);
    v.z += __shfl_down(v.z, off);
    v.w += __shfl_down(v.w, off);
  }
  __syncthreads();  // protect `red` against previous use
  if ((tid & 63) == 0) {
    const int w = tid >> 6;
    red[w * 4 + 0] = v.x; red[w * 4 + 1] = v.y;
    red[w * 4 + 2] = v.z; red[w * 4 + 3] = v.w;
  }
  __syncthreads();
  return make_float4(red[0] + red[4] + red[8]  + red[12],
                     red[1] + red[5] + red[9]  + red[13],
                     red[2] + red[6] + red[10] + red[14],
                     red[3] + red[7] + red[11] + red[15]);
}

__global__ __launch_bounds__(256) void ln_gate_kernel(
    const __hip_bfloat16* __restrict__ G, const float* __restrict__ h,
    const float* __restrict__ b0, const float* __restrict__ b1,
    const float* __restrict__ b2, const float* __restrict__ b3,
    float* __restrict__ out)
{
  const int row = blockIdx.x;
  const int t   = threadIdx.x;
  const unsigned short* g = (const unsigned short*)(G + (size_t)row * 3072);

  __shared__ float zr[1024];
  __shared__ float red[16];

  float v0[4], v1[4];
  {
    const ushort4 u = *(const ushort4*)(g + 4 * t);
    const float4 b = *(const float4*)(b0 + 4 * t);
    v0[0] = bfraw2f(u.x) + b.x; v0[1] = bfraw2f(u.y) + b.y;
    v0[2] = bfraw2f(u.z) + b.z; v0[3] = bfraw2f(u.w) + b.w;
  }
  {
    const ushort4 u = *(const ushort4*)(g + 1024 + 4 * t);
    const float4 b = *(const float4*)(b1 + 4 * t);
    v1[0] = bfraw2f(u.x) + b.x; v1[1] = bfraw2f(u.y) + b.y;
    v1[2] = bfraw2f(u.z) + b.z; v1[3] = bfraw2f(u.w) + b.w;
  }
  float4 a;
  a.x = v0[0] + v0[1] + v0[2] + v0[3];
  a.y = v0[0]*v0[0] + v0[1]*v0[1] + v0[2]*v0[2] + v0[3]*v0[3];
  a.z = v1[0] + v1[1] + v1[2] + v1[3];
  a.w = v1[0]*v1[0] + v1[1]*v1[1] + v1[2]*v1[2] + v1[3]*v1[3];
  const float4 r01 = block_red4(a, red, t);
  const float mu0 = r01.x * (1.f / 1024.f);
  const float mu1 = r01.z * (1.f / 1024.f);
  const float rs0 = rsqrtf(r01.y * (1.f / 1024.f) - mu0 * mu0 + 1e-5f);
  const float rs1 = rsqrtf(r01.w * (1.f / 1024.f) - mu1 * mu1 + 1e-5f);

#pragma unroll
  for (int k = 0; k < 4; ++k) {
    const float pre = (v0[k] - mu0) * rs0 + (v1[k] - mu1) * rs1;
    zr[4 * t + k] = 1.f / (1.f + __expf(-pre));
  }

  float v2[2], v3[2];
  {
    const ushort2 u = *(const ushort2*)(g + 2048 + 2 * t);
    const float2 b = *(const float2*)(b2 + 2 * t);
    v2[0] = bfraw2f(u.x) + b.x; v2[1] = bfraw2f(u.y) + b.y;
  }
  {
    const ushort2 u = *(const ushort2*)(g + 2560 + 2 * t);
    const float2 b = *(const float2*)(b3 + 2 * t);
    v3[0] = bfraw2f(u.x) + b.x; v3[1] = bfraw2f(u.y) + b.y;
  }
  a.x = v2[0] + v2[1];
  a.y = v2[0]*v2[0] + v2[1]*v2[1];
  a.z = v3[0] + v3[1];
  a.w = v3[0]*v3[0] + v3[1]*v3[1];
  const float4 r23 = block_red4(a, red, t);  // syncs also publish zr[]
  const float mu2 = r23.x * (1.f / 512.f);
  const float mu3 = r23.z * (1.f / 512.f);
  const float rs2 = rsqrtf(r23.y * (1.f / 512.f) - mu2 * mu2 + 1e-5f);
  const float rs3 = rsqrtf(r23.w * (1.f / 512.f) - mu3 * mu3 + 1e-5f);

  const float2 hv = *(const float2*)(h + (size_t)row * 512 + 2 * t);
  float o[2];
#pragma unroll
  for (int k = 0; k < 2; ++k) {
    const int j = 2 * t + k;
    const float ha = (v2[k] - mu2) * rs2;
    const float hb = (v3[k] - mu3) * rs3;
    const float hhat = tanhf(ha + zr[512 + j] * hb);
    const float z = zr[j];
    const float hvk = (k == 0) ? hv.x : hv.y;
    o[k] = (1.f - z) * hvk + z * hhat;
  }
  *(float2*)(out + (size_t)row * 512 + 2 * t) = make_float2(o[0], o[1]);
}

// ------------------------------- launcher ----------------------------------
extern "C" void kernel_launch(void* const* d_in, const int* in_sizes, int n_in,
                              void* d_out, int out_size, void* d_ws, size_t ws_size,
                              hipStream_t stream) {
  (void)in_sizes; (void)n_in; (void)out_size; (void)ws_size;
  const float* x      = (const float*)d_in[0];
  const float* h      = (const float*)d_in[1];
  const float* W_i2h  = (const float*)d_in[2];
  const float* b_i2h  = (const float*)d_in[3];
  const float* W_h2h  = (const float*)d_in[4];
  const float* b_h2h  = (const float*)d_in[5];
  const float* W_hatW = (const float*)d_in[6];
  const float* b_hatW = (const float*)d_in[7];
  const float* W_hatU = (const float*)d_in[8];
  const float* b_hatU = (const float*)d_in[9];
  float* out = (float*)d_out;
  __hip_bfloat16* ws = (__hip_bfloat16*)d_ws;

  convert_kernel<<<17920, 256, 0, stream>>>(x, h, W_i2h, W_h2h, W_hatW, W_hatU, ws);
  gemm_kernel<<<768, 512, 0, stream>>>(ws + XB_OFF, ws + HB_OFF,
                                       ws + WB_OFF, ws + GB_OFF);
  ln_gate_kernel<<<16384, 256, 0, stream>>>(ws + GB_OFF, h, b_i2h, b_h2h,
                                            b_hatW, b_hatU, out);
}

// Round 7
// 128.637 us; speedup vs baseline: 5.3708x; 5.3708x over previous
//
#include <hip/hip_runtime.h>
#include <hip/hip_bf16.h>

// ---------------------------------------------------------------------------
// LayerNormGRUCell: B=16384, I=H=512
//   G = [x@W_i2h.T | h@W_h2h.T | x@W_hatW.T | h@W_hatU.T]  (16384 x 3072)
//   then per-row: LN segments + gates + tanh + lerp -> h_t (16384 x 512 fp32)
// ws layout (bf16 elements):
//   xb   @ 0         (16384*512)
//   hb   @ 8388608   (16384*512)
//   Wcat @ 16777216  (3072*512)   rows: [W_i2h;W_h2h;W_hatW;W_hatU]
//   Gb   @ 18350080  (16384*3072)
// ---------------------------------------------------------------------------

using f32x4 = __attribute__((ext_vector_type(4))) float;
using s16x8 = __attribute__((ext_vector_type(8))) short;

#define XB_OFF   0ull
#define HB_OFF   8388608ull
#define WB_OFF   16777216ull
#define GB_OFF   18350080ull

// vec4 segment boundaries for the convert kernel
#define CV_X_END   2097152ull
#define CV_H_END   4194304ull
#define CV_W0_END  4325376ull
#define CV_W1_END  4456448ull
#define CV_W2_END  4521984ull
#define CV_W3_END  4587520ull

__device__ __forceinline__ void async_load16(const void* g, void* l) {
  __builtin_amdgcn_global_load_lds(
      (const __attribute__((address_space(1))) unsigned int*)g,
      (__attribute__((address_space(3))) unsigned int*)l, 16, 0, 0);
}

__device__ __forceinline__ float bfraw2f(unsigned short u) {
  union { unsigned int i; float f; } c;
  c.i = ((unsigned int)u) << 16;
  return c.f;
}

// -------------------------- fp32 -> bf16 conversion ------------------------
__global__ __launch_bounds__(256) void convert_kernel(
    const float* __restrict__ x, const float* __restrict__ h,
    const float* __restrict__ w0, const float* __restrict__ w1,
    const float* __restrict__ w2, const float* __restrict__ w3,
    __hip_bfloat16* __restrict__ ws)
{
  const size_t i = (size_t)blockIdx.x * 256 + threadIdx.x;  // vec4 index
  const float* src;
  __hip_bfloat16* dst;
  size_t o;
  if (i < CV_X_END)        { src = x;  dst = ws + XB_OFF;            o = i; }
  else if (i < CV_H_END)   { src = h;  dst = ws + HB_OFF;            o = i - CV_X_END; }
  else if (i < CV_W0_END)  { src = w0; dst = ws + WB_OFF;            o = i - CV_H_END; }
  else if (i < CV_W1_END)  { src = w1; dst = ws + WB_OFF + 524288;   o = i - CV_W0_END; }
  else if (i < CV_W2_END)  { src = w2; dst = ws + WB_OFF + 1048576;  o = i - CV_W1_END; }
  else                     { src = w3; dst = ws + WB_OFF + 1310720;  o = i - CV_W2_END; }
  const float4 v = *(const float4*)(src + 4 * o);
  __hip_bfloat16 t4[4] = {__float2bfloat16(v.x), __float2bfloat16(v.y),
                          __float2bfloat16(v.z), __float2bfloat16(v.w)};
  *(uint2*)(dst + 4 * o) = *(const uint2*)t4;
}

// -------------------------------- GEMM -------------------------------------
// 128x256 tile, BK=32, 8 waves (2Mx4N, per-wave 64x64, acc[4][4]=64 regs),
// 3-slot LDS ring (72 KiB) -> 2 blocks/CU co-resident (16 waves/CU): block-
// level overlap hides prologue/epilogue/drain bubbles (m97/m114 mechanism).
// Counted vmcnt(3): stage depth 2, never drained mid-loop (T4).
// T1 XCD swizzle, T2 XOR-swizzled LDS, T5 setprio. Full K-loop unroll.
// __launch_bounds__(512,4) caps regs at 128/wave -- per-wave state fits:
// acc 64 + frags 32 + addressing ~20 (round-6 lesson: 256^2 tile cannot).
//
// LDS slot (per matrix): [rows][32 bf16 = 64 B]; physical column byte cb
// holds global k-byte (cb ^ swz(row)), swz(row) = ((row>>1)&3)<<4.
// global_load_lds writes linearly; source global address pre-swizzled;
// ds_read applies the same XOR (rule 21). For both staging and reads the
// XOR reduces to a per-lane constant (row bases are multiples of 8).
//
// WAR safety: stage(t+2) targets slot (t+2)%3 == slot (t-1)%3, whose reads
// completed before this ktile's entry barrier.

#define ASLOT_BYTES 8192     // 128*64
#define BSLOT_BYTES 16384    // 256*64
#define RING_STRIDE 24576    // A slot + B slot
// ring: slot s at lds + s*RING_STRIDE (A), + ASLOT_BYTES (B)

__device__ __forceinline__ void stage_A(const char* base, char* slot,
                                        int koff, int wave, int lane) {
  const int row  = wave * 16 + (lane >> 2);
  const int colb = ((lane & 3) * 16) ^ (((lane >> 3) & 3) << 4);  // pre-swz
  async_load16(base + (size_t)row * 1024 + koff + colb,
               slot + wave * 1024 + lane * 16);
}
__device__ __forceinline__ void stage_B(const char* base, char* slot,
                                        int koff, int wave, int lane) {
#pragma unroll
  for (int i = 0; i < 2; ++i) {
    const int c = wave * 2 + i;
    const int row  = c * 16 + (lane >> 2);
    const int colb = ((lane & 3) * 16) ^ (((lane >> 3) & 3) << 4);
    async_load16(base + (size_t)row * 1024 + koff + colb,
                 slot + c * 1024 + lane * 16);
  }
}

__global__ __launch_bounds__(512, 4) void gemm_kernel(
    const __hip_bfloat16* __restrict__ xb,
    const __hip_bfloat16* __restrict__ hb,
    const __hip_bfloat16* __restrict__ Wb,
    __hip_bfloat16* __restrict__ G)
{
  // T1: bijective XCD swizzle; nwg=1536, 1536%8==0, chunk=192 wgs/XCD.
  // n-tile fastest (12 B-panels = 3 MB, fits 4 MB L2/XCD).
  const int bid = blockIdx.x;
  const int wg  = (bid & 7) * 192 + (bid >> 3);
  const int ntl = wg % 12, mtl = wg / 12;
  const int m0 = mtl * 128, n0 = ntl * 256;
  const int seg = n0 >> 9;  // 512-wide segments: 0,1,4 -> x ; 2,3,5 -> h
  const __hip_bfloat16* A = (seg < 2 || seg == 4) ? xb : hb;

  __shared__ __align__(16) char lds[73728];  // 3 x (A 8K + B 16K)

  const int tid  = threadIdx.x;
  const int lane = tid & 63;
  const int wave = tid >> 6;
  const int wm = wave >> 2, wn = wave & 3;   // 2 x 4 wave grid, 64x64 each

  const char* Ab = (const char*)A  + (size_t)m0 * 1024;  // row = 512*2 B
  const char* Bb = (const char*)Wb + (size_t)n0 * 1024;

  const int lk   = (lane >> 4) * 16;               // k-quarter byte offset
  const int lr   = lane & 15;
  const int swzc = ((lr >> 1) & 3) << 4;           // per-lane read swizzle
  const int rdk  = lk ^ swzc;

  auto rdA = [&](int fm, int slot) {
    return *(const s16x8*)(lds + slot * RING_STRIDE +
                           (wm * 64 + fm * 16 + lr) * 64 + rdk);
  };
  auto rdB = [&](int fn, int slot) {
    return *(const s16x8*)(lds + slot * RING_STRIDE + ASLOT_BYTES +
                           (wn * 64 + fn * 16 + lr) * 64 + rdk);
  };

  f32x4 acc[4][4];
#pragma unroll
  for (int i = 0; i < 4; ++i)
#pragma unroll
    for (int j = 0; j < 4; ++j) acc[i][j] = (f32x4){0.f, 0.f, 0.f, 0.f};

  // prologue: stage slots 0,1 (3 loads each -> 6 outstanding)
  stage_A(Ab, lds, 0, wave, lane);
  stage_B(Bb, lds + ASLOT_BYTES, 0, wave, lane);
  stage_A(Ab, lds + RING_STRIDE, 64, wave, lane);
  stage_B(Bb, lds + RING_STRIDE + ASLOT_BYTES, 64, wave, lane);

  // K = 512 = 16 ktiles of 32, fully unrolled (static slot indices)
#pragma unroll
  for (int t = 0; t < 16; ++t) {
    if (t < 15) asm volatile("s_waitcnt vmcnt(3)" ::: "memory");  // slot t ok
    else        asm volatile("s_waitcnt vmcnt(0)" ::: "memory");
    __builtin_amdgcn_s_barrier();   // slot t fully written; slot (t-1) reads done

    const int slot = t % 3;
    s16x8 b[4], a[4];
#pragma unroll
    for (int fn = 0; fn < 4; ++fn) b[fn] = rdB(fn, slot);
#pragma unroll
    for (int fm = 0; fm < 4; ++fm) a[fm] = rdA(fm, slot);

    if (t <= 13) {  // stage slot t+2 into ring pos (t+2)%3
      char* s = lds + ((t + 2) % 3) * RING_STRIDE;
      stage_A(Ab, s, (t + 2) * 64, wave, lane);
      stage_B(Bb, s + ASLOT_BYTES, (t + 2) * 64, wave, lane);
    }

    __builtin_amdgcn_s_setprio(1);
#pragma unroll
    for (int fm = 0; fm < 4; ++fm)
#pragma unroll
      for (int fn = 0; fn < 4; ++fn)
        acc[fm][fn] = __builtin_amdgcn_mfma_f32_16x16x32_bf16(
            a[fm], b[fn], acc[fm][fn], 0, 0, 0);
    __builtin_amdgcn_s_setprio(0);
  }

  // epilogue: D lane map (verified): col = lane&15, row = (lane>>4)*4 + reg
  const int mbase = m0 + wm * 64 + ((lane >> 4) << 2);
  const int nbase = n0 + wn * 64 + (lane & 15);
#pragma unroll
  for (int fm = 0; fm < 4; ++fm)
#pragma unroll
    for (int fn = 0; fn < 4; ++fn)
#pragma unroll
      for (int r = 0; r < 4; ++r)
        G[(size_t)(mbase + fm * 16 + r) * 3072 + nbase + fn * 16] =
            __float2bfloat16(acc[fm][fn][r]);
}

// ------------------------------ LN + gates ---------------------------------
__device__ __forceinline__ float4 block_red4(float4 v, float* red, int tid) {
#pragma unroll
  for (int off = 32; off; off >>= 1) {
    v.x += __shfl_down(v.x, off);
    v.y += __shfl_down(v.y, off);
    v.z += __shfl_down(v.z, off);
    v.w += __shfl_down(v.w, off);
  }
  __syncthreads();  // protect `red` against previous use
  if ((tid & 63) == 0) {
    const int w = tid >> 6;
    red[w * 4 + 0] = v.x; red[w * 4 + 1] = v.y;
    red[w * 4 + 2] = v.z; red[w * 4 + 3] = v.w;
  }
  __syncthreads();
  return make_float4(red[0] + red[4] + red[8]  + red[12],
                     red[1] + red[5] + red[9]  + red[13],
                     red[2] + red[6] + red[10] + red[14],
                     red[3] + red[7] + red[11] + red[15]);
}

__global__ __launch_bounds__(256) void ln_gate_kernel(
    const __hip_bfloat16* __restrict__ G, const float* __restrict__ h,
    const float* __restrict__ b0, const float* __restrict__ b1,
    const float* __restrict__ b2, const float* __restrict__ b3,
    float* __restrict__ out)
{
  const int row = blockIdx.x;
  const int t   = threadIdx.x;
  const unsigned short* g = (const unsigned short*)(G + (size_t)row * 3072);

  __shared__ float zr[1024];
  __shared__ float red[16];

  float v0[4], v1[4];
  {
    const ushort4 u = *(const ushort4*)(g + 4 * t);
    const float4 b = *(const float4*)(b0 + 4 * t);
    v0[0] = bfraw2f(u.x) + b.x; v0[1] = bfraw2f(u.y) + b.y;
    v0[2] = bfraw2f(u.z) + b.z; v0[3] = bfraw2f(u.w) + b.w;
  }
  {
    const ushort4 u = *(const ushort4*)(g + 1024 + 4 * t);
    const float4 b = *(const float4*)(b1 + 4 * t);
    v1[0] = bfraw2f(u.x) + b.x; v1[1] = bfraw2f(u.y) + b.y;
    v1[2] = bfraw2f(u.z) + b.z; v1[3] = bfraw2f(u.w) + b.w;
  }
  float4 a;
  a.x = v0[0] + v0[1] + v0[2] + v0[3];
  a.y = v0[0]*v0[0] + v0[1]*v0[1] + v0[2]*v0[2] + v0[3]*v0[3];
  a.z = v1[0] + v1[1] + v1[2] + v1[3];
  a.w = v1[0]*v1[0] + v1[1]*v1[1] + v1[2]*v1[2] + v1[3]*v1[3];
  const float4 r01 = block_red4(a, red, t);
  const float mu0 = r01.x * (1.f / 1024.f);
  const float mu1 = r01.z * (1.f / 1024.f);
  const float rs0 = rsqrtf(r01.y * (1.f / 1024.f) - mu0 * mu0 + 1e-5f);
  const float rs1 = rsqrtf(r01.w * (1.f / 1024.f) - mu1 * mu1 + 1e-5f);

#pragma unroll
  for (int k = 0; k < 4; ++k) {
    const float pre = (v0[k] - mu0) * rs0 + (v1[k] - mu1) * rs1;
    zr[4 * t + k] = 1.f / (1.f + __expf(-pre));
  }

  float v2[2], v3[2];
  {
    const ushort2 u = *(const ushort2*)(g + 2048 + 2 * t);
    const float2 b = *(const float2*)(b2 + 2 * t);
    v2[0] = bfraw2f(u.x) + b.x; v2[1] = bfraw2f(u.y) + b.y;
  }
  {
    const ushort2 u = *(const ushort2*)(g + 2560 + 2 * t);
    const float2 b = *(const float2*)(b3 + 2 * t);
    v3[0] = bfraw2f(u.x) + b.x; v3[1] = bfraw2f(u.y) + b.y;
  }
  a.x = v2[0] + v2[1];
  a.y = v2[0]*v2[0] + v2[1]*v2[1];
  a.z = v3[0] + v3[1];
  a.w = v3[0]*v3[0] + v3[1]*v3[1];
  const float4 r23 = block_red4(a, red, t);  // syncs also publish zr[]
  const float mu2 = r23.x * (1.f / 512.f);
  const float mu3 = r23.z * (1.f / 512.f);
  const float rs2 = rsqrtf(r23.y * (1.f / 512.f) - mu2 * mu2 + 1e-5f);
  const float rs3 = rsqrtf(r23.w * (1.f / 512.f) - mu3 * mu3 + 1e-5f);

  const float2 hv = *(const float2*)(h + (size_t)row * 512 + 2 * t);
  float o[2];
#pragma unroll
  for (int k = 0; k < 2; ++k) {
    const int j = 2 * t + k;
    const float ha = (v2[k] - mu2) * rs2;
    const float hb = (v3[k] - mu3) * rs3;
    const float hhat = tanhf(ha + zr[512 + j] * hb);
    const float z = zr[j];
    const float hvk = (k == 0) ? hv.x : hv.y;
    o[k] = (1.f - z) * hvk + z * hhat;
  }
  *(float2*)(out + (size_t)row * 512 + 2 * t) = make_float2(o[0], o[1]);
}

// ------------------------------- launcher ----------------------------------
extern "C" void kernel_launch(void* const* d_in, const int* in_sizes, int n_in,
                              void* d_out, int out_size, void* d_ws, size_t ws_size,
                              hipStream_t stream) {
  (void)in_sizes; (void)n_in; (void)out_size; (void)ws_size;
  const float* x      = (const float*)d_in[0];
  const float* h      = (const float*)d_in[1];
  const float* W_i2h  = (const float*)d_in[2];
  const float* b_i2h  = (const float*)d_in[3];
  const float* W_h2h  = (const float*)d_in[4];
  const float* b_h2h  = (const float*)d_in[5];
  const float* W_hatW = (const float*)d_in[6];
  const float* b_hatW = (const float*)d_in[7];
  const float* W_hatU = (const float*)d_in[8];
  const float* b_hatU = (const float*)d_in[9];
  float* out = (float*)d_out;
  __hip_bfloat16* ws = (__hip_bfloat16*)d_ws;

  convert_kernel<<<17920, 256, 0, stream>>>(x, h, W_i2h, W_h2h, W_hatW, W_hatU, ws);
  gemm_kernel<<<1536, 512, 0, stream>>>(ws + XB_OFF, ws + HB_OFF,
                                        ws + WB_OFF, ws + GB_OFF);
  ln_gate_kernel<<<16384, 256, 0, stream>>>(ws + GB_OFF, h, b_i2h, b_h2h,
                                            b_hatW, b_hatU, out);
}

// Round 8
// 123.718 us; speedup vs baseline: 5.5843x; 1.0398x over previous
//
#include <hip/hip_runtime.h>
#include <hip/hip_bf16.h>

// ---------------------------------------------------------------------------
// LayerNormGRUCell: B=16384, I=H=512
//   G = [x@W_i2h.T | h@W_h2h.T | x@W_hatW.T | h@W_hatU.T]  (16384 x 3072)
//   then per-row: LN segments + gates + tanh + lerp -> h_t (16384 x 512 fp32)
// ws layout (bf16 elements):
//   Wcat @ 0        (3072*512)    rows: [W_i2h;W_h2h;W_hatW;W_hatU]
//   Gb   @ 1572864  (16384*3072)
// x/h are consumed as fp32 directly by the GEMM (in-register bf16 convert
// during staging) -- the 200MB convert round-trip for x/h is eliminated.
// ---------------------------------------------------------------------------

using f32x4 = __attribute__((ext_vector_type(4))) float;
using s16x8 = __attribute__((ext_vector_type(8))) short;

#define WB_OFF   0ull
#define GB_OFF   1572864ull

__device__ __forceinline__ void async_load16(const void* g, void* l) {
  __builtin_amdgcn_global_load_lds(
      (const __attribute__((address_space(1))) unsigned int*)g,
      (__attribute__((address_space(3))) unsigned int*)l, 16, 0, 0);
}

__device__ __forceinline__ float bfraw2f(unsigned short u) {
  union { unsigned int i; float f; } c;
  c.i = ((unsigned int)u) << 16;
  return c.f;
}

// -------------------------- fp32 -> bf16 weights only ----------------------
// vec4 boundaries: w0 131072, w1 +131072, w2 +65536, w3 +65536 = 393216 total
__global__ __launch_bounds__(256) void convert_w_kernel(
    const float* __restrict__ w0, const float* __restrict__ w1,
    const float* __restrict__ w2, const float* __restrict__ w3,
    __hip_bfloat16* __restrict__ dst)
{
  const size_t i = (size_t)blockIdx.x * 256 + threadIdx.x;  // vec4 index
  const float* src;
  __hip_bfloat16* d;
  size_t o;
  if (i < 131072ull)      { src = w0; d = dst;            o = i; }
  else if (i < 262144ull) { src = w1; d = dst + 524288;   o = i - 131072ull; }
  else if (i < 327680ull) { src = w2; d = dst + 1048576;  o = i - 262144ull; }
  else                    { src = w3; d = dst + 1310720;  o = i - 327680ull; }
  const float4 v = *(const float4*)(src + 4 * o);
  __hip_bfloat16 t4[4] = {__float2bfloat16(v.x), __float2bfloat16(v.y),
                          __float2bfloat16(v.z), __float2bfloat16(v.w)};
  *(uint2*)(d + 4 * o) = *(const uint2*)t4;
}

// -------------------------------- GEMM -------------------------------------
// 128x256 tile, BK=32, 8 waves (2Mx4N, per-wave 64x64), 3-slot LDS ring
// (72 KiB) -> 2 blocks/CU. A is REG-STAGED from fp32 (global dwordx4 ->
// __float2bfloat16 -> swizzled ds_write_b128; T14 split: loads before MFMA,
// write after). B staged bf16 via global_load_lds (pre-swizzled source).
// Counted entry wait vmcnt(2)+lgkmcnt(0) (T4): writeA's auto-wait leaves only
// the current ktile's 2 B-glds outstanding. T1 XCD swizzle, T2 XOR swizzle,
// T5 setprio. Full K-loop unroll.
//
// LDS slot (per matrix): [rows][32 bf16 = 64 B]; byte cb of row holds global
// k-byte cb ^ swz(row), swz(row) = ((row>>1)&3)<<4. A: swizzled ds_write +
// swizzled ds_read. B: pre-swizzled global source + linear gload_lds dest +
// swizzled ds_read (both rule-21 consistent).
//
// WAR safety: slot (t+2)%3 == slot (t-1)%3, whose reads retired before this
// ktile's entry barrier; A ds_write/B glds for it issue after that barrier.

#define ASLOT_BYTES 8192     // 128*64
#define RING_STRIDE 24576    // A slot (8K) + B slot (16K)

__device__ __forceinline__ void stage_B(const char* base, char* slot,
                                        int koff, int wave, int lane) {
#pragma unroll
  for (int i = 0; i < 2; ++i) {
    const int c = wave * 2 + i;
    const int row  = c * 16 + (lane >> 2);
    const int colb = ((lane & 3) * 16) ^ (((lane >> 3) & 3) << 4);  // pre-swz
    async_load16(base + (size_t)row * 1024 + koff + colb,
                 slot + c * 1024 + lane * 16);
  }
}

__global__ __launch_bounds__(512, 4) void gemm_kernel(
    const float* __restrict__ xf,
    const float* __restrict__ hf,
    const __hip_bfloat16* __restrict__ Wb,
    __hip_bfloat16* __restrict__ G)
{
  // T1: bijective XCD swizzle; nwg=1536, 1536%8==0, chunk=192 wgs/XCD.
  const int bid = blockIdx.x;
  const int wg  = (bid & 7) * 192 + (bid >> 3);
  const int ntl = wg % 12, mtl = wg / 12;
  const int m0 = mtl * 128, n0 = ntl * 256;
  const int seg = n0 >> 9;  // 512-wide segments: 0,1,4 -> x ; 2,3,5 -> h
  const float* A = (seg < 2 || seg == 4) ? xf : hf;

  __shared__ __align__(16) char lds[73728];  // 3 x (A 8K + B 16K)

  const int tid  = threadIdx.x;
  const int lane = tid & 63;
  const int wave = tid >> 6;
  const int wm = wave >> 2, wn = wave & 3;   // 2 x 4 wave grid, 64x64 each

  const float* Afp = A + (size_t)m0 * 512;          // fp32, row stride 512
  const char*  Bb  = (const char*)Wb + (size_t)n0 * 1024;

  // A reg-staging addressing: thread -> (row = tid>>2, 8 fp32 at col (tid&3)*8)
  const int arow = tid >> 2;
  const float* aptr = Afp + (size_t)arow * 512 + (tid & 3) * 8;
  const int awr_off = arow * 64 + (((tid & 3) * 16) ^ (((arow >> 1) & 3) << 4));

  const int lk  = (lane >> 4) * 16;
  const int lr  = lane & 15;
  const int rdk = lk ^ (((lr >> 1) & 3) << 4);     // per-lane read swizzle

  auto rdA = [&](int fm, int slot) {
    return *(const s16x8*)(lds + slot * RING_STRIDE +
                           (wm * 64 + fm * 16 + lr) * 64 + rdk);
  };
  auto rdB = [&](int fn, int slot) {
    return *(const s16x8*)(lds + slot * RING_STRIDE + ASLOT_BYTES +
                           (wn * 64 + fn * 16 + lr) * 64 + rdk);
  };
  auto loadA = [&](int t, float4& f0, float4& f1) {
    const float* p = aptr + t * 32;
    f0 = *(const float4*)p;
    f1 = *(const float4*)(p + 4);
  };
  auto writeA = [&](int t, const float4& f0, const float4& f1) {
    union { s16x8 v; __hip_bfloat16 b[8]; } u;
    u.b[0] = __float2bfloat16(f0.x); u.b[1] = __float2bfloat16(f0.y);
    u.b[2] = __float2bfloat16(f0.z); u.b[3] = __float2bfloat16(f0.w);
    u.b[4] = __float2bfloat16(f1.x); u.b[5] = __float2bfloat16(f1.y);
    u.b[6] = __float2bfloat16(f1.z); u.b[7] = __float2bfloat16(f1.w);
    *(s16x8*)(lds + (t % 3) * RING_STRIDE + awr_off) = u.v;
  };

  f32x4 acc[4][4];
#pragma unroll
  for (int i = 0; i < 4; ++i)
#pragma unroll
    for (int j = 0; j < 4; ++j) acc[i][j] = (f32x4){0.f, 0.f, 0.f, 0.f};

  // prologue: slots 0,1. Issue A loads + B glds, convert/write A, counted wait.
  {
    float4 a00, a01, a10, a11;
    loadA(0, a00, a01);
    loadA(1, a10, a11);
    stage_B(Bb, lds + ASLOT_BYTES, 0, wave, lane);
    stage_B(Bb, lds + RING_STRIDE + ASLOT_BYTES, 64, wave, lane);
    writeA(0, a00, a01);   // auto vmcnt waits drain the A loads only
    writeA(1, a10, a11);
    asm volatile("s_waitcnt vmcnt(2) lgkmcnt(0)" ::: "memory");  // slot0 B done
    __builtin_amdgcn_s_barrier();
  }

  // K = 512 = 16 ktiles of 32, fully unrolled (static slot indices)
#pragma unroll
  for (int t = 0; t < 16; ++t) {
    if (t > 0) {
      // outstanding at entry: B glds for slot t+1 (2 ops). Slot t's B is
      // older -> drained by vmcnt(2); A(t) write drained by lgkmcnt(0).
      if (t <= 14) asm volatile("s_waitcnt vmcnt(2) lgkmcnt(0)" ::: "memory");
      else         asm volatile("s_waitcnt vmcnt(0) lgkmcnt(0)" ::: "memory");
      __builtin_amdgcn_s_barrier();
    }

    const int slot = t % 3;
    s16x8 b[4], a[4];
#pragma unroll
    for (int fn = 0; fn < 4; ++fn) b[fn] = rdB(fn, slot);
#pragma unroll
    for (int fm = 0; fm < 4; ++fm) a[fm] = rdA(fm, slot);

    float4 f0, f1;
    if (t <= 13) {  // issue next-next staging: A fp32 -> regs, B -> LDS
      loadA(t + 2, f0, f1);
      stage_B(Bb, lds + ((t + 2) % 3) * RING_STRIDE + ASLOT_BYTES,
              (t + 2) * 64, wave, lane);
    }

    __builtin_amdgcn_s_setprio(1);
#pragma unroll
    for (int fm = 0; fm < 4; ++fm)
#pragma unroll
      for (int fn = 0; fn < 4; ++fn)
        acc[fm][fn] = __builtin_amdgcn_mfma_f32_16x16x32_bf16(
            a[fm], b[fn], acc[fm][fn], 0, 0, 0);
    __builtin_amdgcn_s_setprio(0);

    if (t <= 13) writeA(t + 2, f0, f1);  // T14: HBM latency hid under MFMAs
  }

  // epilogue: D lane map (verified): col = lane&15, row = (lane>>4)*4 + reg
  const int mbase = m0 + wm * 64 + ((lane >> 4) << 2);
  const int nbase = n0 + wn * 64 + (lane & 15);
#pragma unroll
  for (int fm = 0; fm < 4; ++fm)
#pragma unroll
    for (int fn = 0; fn < 4; ++fn)
#pragma unroll
      for (int r = 0; r < 4; ++r)
        G[(size_t)(mbase + fm * 16 + r) * 3072 + nbase + fn * 16] =
            __float2bfloat16(acc[fm][fn][r]);
}

// ------------------------------ LN + gates ---------------------------------
__device__ __forceinline__ float4 block_red4(float4 v, float* red, int tid) {
#pragma unroll
  for (int off = 32; off; off >>= 1) {
    v.x += __shfl_down(v.x, off);
    v.y += __shfl_down(v.y, off);
    v.z += __shfl_down(v.z, off);
    v.w += __shfl_down(v.w, off);
  }
  __syncthreads();  // protect `red` against previous use
  if ((tid & 63) == 0) {
    const int w = tid >> 6;
    red[w * 4 + 0] = v.x; red[w * 4 + 1] = v.y;
    red[w * 4 + 2] = v.z; red[w * 4 + 3] = v.w;
  }
  __syncthreads();
  return make_float4(red[0] + red[4] + red[8]  + red[12],
                     red[1] + red[5] + red[9]  + red[13],
                     red[2] + red[6] + red[10] + red[14],
                     red[3] + red[7] + red[11] + red[15]);
}

__global__ __launch_bounds__(256) void ln_gate_kernel(
    const __hip_bfloat16* __restrict__ G, const float* __restrict__ h,
    const float* __restrict__ b0, const float* __restrict__ b1,
    const float* __restrict__ b2, const float* __restrict__ b3,
    float* __restrict__ out)
{
  const int row = blockIdx.x;
  const int t   = threadIdx.x;
  const unsigned short* g = (const unsigned short*)(G + (size_t)row * 3072);

  __shared__ float zr[1024];
  __shared__ float red[16];

  float v0[4], v1[4];
  {
    const ushort4 u = *(const ushort4*)(g + 4 * t);
    const float4 b = *(const float4*)(b0 + 4 * t);
    v0[0] = bfraw2f(u.x) + b.x; v0[1] = bfraw2f(u.y) + b.y;
    v0[2] = bfraw2f(u.z) + b.z; v0[3] = bfraw2f(u.w) + b.w;
  }
  {
    const ushort4 u = *(const ushort4*)(g + 1024 + 4 * t);
    const float4 b = *(const float4*)(b1 + 4 * t);
    v1[0] = bfraw2f(u.x) + b.x; v1[1] = bfraw2f(u.y) + b.y;
    v1[2] = bfraw2f(u.z) + b.z; v1[3] = bfraw2f(u.w) + b.w;
  }
  float4 a;
  a.x = v0[0] + v0[1] + v0[2] + v0[3];
  a.y = v0[0]*v0[0] + v0[1]*v0[1] + v0[2]*v0[2] + v0[3]*v0[3];
  a.z = v1[0] + v1[1] + v1[2] + v1[3];
  a.w = v1[0]*v1[0] + v1[1]*v1[1] + v1[2]*v1[2] + v1[3]*v1[3];
  const float4 r01 = block_red4(a, red, t);
  const float mu0 = r01.x * (1.f / 1024.f);
  const float mu1 = r01.z * (1.f / 1024.f);
  const float rs0 = rsqrtf(r01.y * (1.f / 1024.f) - mu0 * mu0 + 1e-5f);
  const float rs1 = rsqrtf(r01.w * (1.f / 1024.f) - mu1 * mu1 + 1e-5f);

#pragma unroll
  for (int k = 0; k < 4; ++k) {
    const float pre = (v0[k] - mu0) * rs0 + (v1[k] - mu1) * rs1;
    zr[4 * t + k] = 1.f / (1.f + __expf(-pre));
  }

  float v2[2], v3[2];
  {
    const ushort2 u = *(const ushort2*)(g + 2048 + 2 * t);
    const float2 b = *(const float2*)(b2 + 2 * t);
    v2[0] = bfraw2f(u.x) + b.x; v2[1] = bfraw2f(u.y) + b.y;
  }
  {
    const ushort2 u = *(const ushort2*)(g + 2560 + 2 * t);
    const float2 b = *(const float2*)(b3 + 2 * t);
    v3[0] = bfraw2f(u.x) + b.x; v3[1] = bfraw2f(u.y) + b.y;
  }
  a.x = v2[0] + v2[1];
  a.y = v2[0]*v2[0] + v2[1]*v2[1];
  a.z = v3[0] + v3[1];
  a.w = v3[0]*v3[0] + v3[1]*v3[1];
  const float4 r23 = block_red4(a, red, t);  // syncs also publish zr[]
  const float mu2 = r23.x * (1.f / 512.f);
  const float mu3 = r23.z * (1.f / 512.f);
  const float rs2 = rsqrtf(r23.y * (1.f / 512.f) - mu2 * mu2 + 1e-5f);
  const float rs3 = rsqrtf(r23.w * (1.f / 512.f) - mu3 * mu3 + 1e-5f);

  const float2 hv = *(const float2*)(h + (size_t)row * 512 + 2 * t);
  float o[2];
#pragma unroll
  for (int k = 0; k < 2; ++k) {
    const int j = 2 * t + k;
    const float ha = (v2[k] - mu2) * rs2;
    const float hb = (v3[k] - mu3) * rs3;
    const float hhat = tanhf(ha + zr[512 + j] * hb);
    const float z = zr[j];
    const float hvk = (k == 0) ? hv.x : hv.y;
    o[k] = (1.f - z) * hvk + z * hhat;
  }
  *(float2*)(out + (size_t)row * 512 + 2 * t) = make_float2(o[0], o[1]);
}

// ------------------------------- launcher ----------------------------------
extern "C" void kernel_launch(void* const* d_in, const int* in_sizes, int n_in,
                              void* d_out, int out_size, void* d_ws, size_t ws_size,
                              hipStream_t stream) {
  (void)in_sizes; (void)n_in; (void)out_size; (void)ws_size;
  const float* x      = (const float*)d_in[0];
  const float* h      = (const float*)d_in[1];
  const float* W_i2h  = (const float*)d_in[2];
  const float* b_i2h  = (const float*)d_in[3];
  const float* W_h2h  = (const float*)d_in[4];
  const float* b_h2h  = (const float*)d_in[5];
  const float* W_hatW = (const float*)d_in[6];
  const float* b_hatW = (const float*)d_in[7];
  const float* W_hatU = (const float*)d_in[8];
  const float* b_hatU = (const float*)d_in[9];
  float* out = (float*)d_out;
  __hip_bfloat16* ws = (__hip_bfloat16*)d_ws;

  convert_w_kernel<<<1536, 256, 0, stream>>>(W_i2h, W_h2h, W_hatW, W_hatU,
                                             ws + WB_OFF);
  gemm_kernel<<<1536, 512, 0, stream>>>(x, h, ws + WB_OFF, ws + GB_OFF);
  ln_gate_kernel<<<16384, 256, 0, stream>>>(ws + GB_OFF, h, b_i2h, b_h2h,
                                            b_hatW, b_hatU, out);
}